// Round 18
// baseline (481.752 us; speedup 1.0000x reference)
//
#include <hip/hip_runtime.h>
#include <cstdint>
#include <cstddef>

// EarthAttention3D (Pangu-Weather): NW=720, L=144, DIM=192, H=6, hd=32
// All matmuls MFMA 16x16x32 bf16, split-bf16 (a = hi+lo; a*b ~= hh+hl+lh).
// Intermediates stored PACKED: one uint per element = (hi_bf16<<16)|lo_bf16.
// MFMA layouts (validated rounds 2-17): A/B row-major [m|n][k], row = lane&15,
// k = (lane>>4)*8 + t. C/D: col(n) = lane&15, row(m) = (lane>>4)*4 + reg.
//
// ROUND 18: FUSE proj into attn. proj decomposes head-wise:
// out[i][c] = sum_u O_u[i][0:32] . w2[c][32u..32u+32]. Block = one window's
// 6 heads (720 blocks, q=(b&7)*90+(b>>3) XCD-bijective), R16/17's sequential
// ring pipeline; after each unit's PV, transpose O through the SAME per-wave
// Scr ([16][40] padded, lockstep lgkmcnt discipline as the P-transpose) and
// accumulate 12 n-tiles x 3 split-MFMA into persistent pacc[12] (48 VGPR,
// rows = wave's i-strip, shared by all 6 units). After unit 5: +b2, write
// fp32 out directly. Eliminates: proj kernel (~50us), prep2-before-proj
// ordering, the aop buffer (its ws region now hosts btT + w2 planes; d_out
// is written only by attn). Numerics identical (O was already split-packed).
// GEMM-qkv unchanged (R7 staged).

using short8 = __attribute__((ext_vector_type(8))) short;
using f32x4  = __attribute__((ext_vector_type(4))) float;

constexpr int kNW = 720;
constexpr float kScale = 0.17677669529663687f;  // 32^-0.5
constexpr size_t kQKVElems = (size_t)kNW * 6 * 144 * 32;  // 19,906,560

__device__ __forceinline__ ushort bf16_rne(float f) {
  uint u = __builtin_bit_cast(uint, f);
  return (ushort)((u + 0x7FFFu + ((u >> 16) & 1u)) >> 16);
}
__device__ __forceinline__ float bf16_to_f(ushort h) {
  uint u = ((uint)h) << 16;
  return __builtin_bit_cast(float, u);
}
__device__ __forceinline__ uint pack_hl(float f) {
  const ushort h = bf16_rne(f);
  const ushort l = bf16_rne(f - bf16_to_f(h));
  return ((uint)h << 16) | l;
}

// ---------------------------------------------------------------------------
// prep: fp32 -> separate (hi,lo) bf16 planes (for weight panels).
// ---------------------------------------------------------------------------
__global__ __launch_bounds__(256) void prep_kernel(
    const float* __restrict__ src, ushort* __restrict__ dh,
    ushort* __restrict__ dl, int n)
{
  const int i = blockIdx.x * 256 + threadIdx.x;
  if (i < n) {
    const float f = src[i];
    const ushort h = bf16_rne(f);
    dh[i] = h;
    dl[i] = bf16_rne(f - bf16_to_f(h));
  }
}

// ---------------------------------------------------------------------------
// btT: transpose bias_table (3312,1440) -> (1440,3312); lives in dead ws.
// ---------------------------------------------------------------------------
__global__ __launch_bounds__(256) void btT_kernel(
    const float* __restrict__ bt, float* __restrict__ btT)
{
  __shared__ float T[48][49];
  const int pb = (blockIdx.x % 69) * 48;
  const int bb = (blockIdx.x / 69) * 48;
  const int tid = threadIdx.x;
  for (int f = tid; f < 2304; f += 256) {
    const int r = f / 48, c = f % 48;
    T[r][c] = bt[(size_t)(pb + r) * 1440 + bb + c];
  }
  __syncthreads();
  for (int f = tid; f < 2304; f += 256) {
    const int r = f % 48, c = f / 48;
    btT[(size_t)(bb + c) * 3312 + pb + r] = T[r][c];
  }
}

// ---------------------------------------------------------------------------
// QKV GEMM (R7 version): BM=128, BN=192, BK=32. 512 thr (8 waves, 2Mx4N).
// A and B staged in LDS. LDS 51.2 KB -> 3 blocks/CU.
// ---------------------------------------------------------------------------
__global__ __launch_bounds__(512) void qkv_gemm_kernel(
    const float* __restrict__ Xf,
    const ushort* __restrict__ Wh, const ushort* __restrict__ Wl,
    const float* __restrict__ bias,
    uint* __restrict__ qp, uint* __restrict__ kp, uint* __restrict__ vp)
{
  __shared__ ushort Ah[128][40], Al[128][40];
  __shared__ ushort Bh[192][40], Bl[192][40];

  const int bid = blockIdx.x;
  const int mtile = bid / 3;
  const int col0  = (bid % 3) * 192;
  const int row0 = mtile * 128;
  const int tid = threadIdx.x;
  const int wave = tid >> 6, lane = tid & 63;
  const int rr = lane & 15, kg = lane >> 4;
  const int wm = wave >> 2, wn = wave & 3;

  f32x4 acc[4][3];
#pragma unroll
  for (int a = 0; a < 4; ++a)
#pragma unroll
    for (int b = 0; b < 3; ++b) acc[a][b] = (f32x4){0.f, 0.f, 0.f, 0.f};

  for (int kc = 0; kc < 192; kc += 32) {
#pragma unroll
    for (int u = 0; u < 2; ++u) {
      const int sl = tid + u * 512;
      const int r = sl >> 3, s = sl & 7;
      float4 xv = *(const float4*)&Xf[(size_t)(row0 + r) * 192 + kc + s * 4];
      ushort4 hv, lv;
      hv.x = bf16_rne(xv.x); lv.x = bf16_rne(xv.x - bf16_to_f(hv.x));
      hv.y = bf16_rne(xv.y); lv.y = bf16_rne(xv.y - bf16_to_f(hv.y));
      hv.z = bf16_rne(xv.z); lv.z = bf16_rne(xv.z - bf16_to_f(hv.z));
      hv.w = bf16_rne(xv.w); lv.w = bf16_rne(xv.w - bf16_to_f(hv.w));
      *(ushort4*)&Ah[r][s * 4] = hv;
      *(ushort4*)&Al[r][s * 4] = lv;
    }
#pragma unroll
    for (int u = 0; u < 3; ++u) {
      const int idx = tid + u * 512;
      const int n = idx >> 3, s2 = idx & 7;
      const size_t g = (size_t)(col0 + n) * 192 + kc + s2 * 4;
      *(uint2*)&Bh[n][s2 * 4] = *(const uint2*)&Wh[g];
      *(uint2*)&Bl[n][s2 * 4] = *(const uint2*)&Wl[g];
    }
    __syncthreads();

    short8 ah[4], al_[4], bh[3], bl[3];
#pragma unroll
    for (int mt = 0; mt < 4; ++mt) {
      const int r = wm * 64 + mt * 16 + rr;
      ah[mt]  = *(const short8*)&Ah[r][kg * 8];
      al_[mt] = *(const short8*)&Al[r][kg * 8];
    }
#pragma unroll
    for (int nt = 0; nt < 3; ++nt) {
      const int n = wn * 48 + nt * 16 + rr;
      bh[nt] = *(const short8*)&Bh[n][kg * 8];
      bl[nt] = *(const short8*)&Bl[n][kg * 8];
    }
#pragma unroll
    for (int mt = 0; mt < 4; ++mt)
#pragma unroll
      for (int nt = 0; nt < 3; ++nt) {
        acc[mt][nt] = __builtin_amdgcn_mfma_f32_16x16x32_bf16(ah[mt],  bh[nt], acc[mt][nt], 0, 0, 0);
        acc[mt][nt] = __builtin_amdgcn_mfma_f32_16x16x32_bf16(ah[mt],  bl[nt], acc[mt][nt], 0, 0, 0);
        acc[mt][nt] = __builtin_amdgcn_mfma_f32_16x16x32_bf16(al_[mt], bh[nt], acc[mt][nt], 0, 0, 0);
      }
    __syncthreads();
  }

  const int t = col0 / 192;
  uint* dst = (t == 0) ? qp : (t == 1) ? kp : vp;
  const float sc = (t == 0) ? kScale : 1.0f;
#pragma unroll
  for (int nt = 0; nt < 3; ++nt) {
    const int c0 = wn * 48 + nt * 16;
    const int hh = c0 >> 5;
    const int d0 = (c0 & 31) + rr;
    const float bcol = bias[col0 + c0 + rr];
#pragma unroll
    for (int mt = 0; mt < 4; ++mt)
#pragma unroll
      for (int reg = 0; reg < 4; ++reg) {
        const int grow = row0 + wm * 64 + mt * 16 + kg * 4 + reg;
        const int w = grow / 144;
        const int l = grow % 144;
        dst[(((size_t)(w * 6 + hh)) * 144 + l) * 32 + d0] =
            pack_hl((acc[mt][nt][reg] + bcol) * sc);
      }
  }
}

// ---------------------------------------------------------------------------
// attn unit body (R7 pipeline) + fused per-head proj partial into pacc[12].
// ---------------------------------------------------------------------------
__device__ __forceinline__ void attn_unit_fused(
    const ushort (&KsH)[144][40], const ushort (&KsL)[144][40],
    const ushort (&VtH)[32][168], const ushort (&VtL)[32][168],
    uint* __restrict__ scrw,
    const uint* __restrict__ qpb, const float* __restrict__ mrow,
    const float* __restrict__ brow,
    const ushort* __restrict__ w2h, const ushort* __restrict__ w2l,
    int u, f32x4* pacc, int wave, int rr, int kg)
{
  const int i0 = wave * 16;
  const int i = i0 + rr;
  const int pi = 828 * (i / 72) + 23 * ((i / 12) % 6) + (i % 12) + 11;

  // preloads (overlap with surrounding work)
  const uint4 qa = *(const uint4*)&qpb[(size_t)i * 32 + kg * 8];
  const uint4 qb = *(const uint4*)&qpb[(size_t)i * 32 + kg * 8 + 4];
  float4 mv[9], bv[9];
#pragma unroll
  for (int jt = 0; jt < 9; ++jt) {
    const int jb = jt * 16 + kg * 4;
    mv[jt] = *(const float4*)&mrow[(size_t)i * 144 + jb];
    const int pjb = 1656 * (jb / 72) + 138 * ((jb / 12) % 6) - (jb % 12);
    bv[jt] = *(const float4*)&brow[pi + pjb - 3];  // {bb-3,bb-2,bb-1,bb}
  }

  union { short8 v; uint uu[4]; } QH, QL;
  QH.uu[0] = (qa.x >> 16) | (qa.y & 0xffff0000u);
  QH.uu[1] = (qa.z >> 16) | (qa.w & 0xffff0000u);
  QH.uu[2] = (qb.x >> 16) | (qb.y & 0xffff0000u);
  QH.uu[3] = (qb.z >> 16) | (qb.w & 0xffff0000u);
  QL.uu[0] = (qa.x & 0xffffu) | (qa.y << 16);
  QL.uu[1] = (qa.z & 0xffffu) | (qa.w << 16);
  QL.uu[2] = (qb.x & 0xffffu) | (qb.y << 16);
  QL.uu[3] = (qb.z & 0xffffu) | (qb.w << 16);

  // Phase 1: S^T = K.Q^T + bias + mask
  f32x4 acc[9];
#pragma unroll
  for (int jt = 0; jt < 9; ++jt) {
    const short8 kah = *(const short8*)&KsH[jt * 16 + rr][kg * 8];
    const short8 kal = *(const short8*)&KsL[jt * 16 + rr][kg * 8];
    f32x4 c = (f32x4){0.f, 0.f, 0.f, 0.f};
    c = __builtin_amdgcn_mfma_f32_16x16x32_bf16(kah, QH.v, c, 0, 0, 0);
    c = __builtin_amdgcn_mfma_f32_16x16x32_bf16(kah, QL.v, c, 0, 0, 0);
    c = __builtin_amdgcn_mfma_f32_16x16x32_bf16(kal, QH.v, c, 0, 0, 0);
    c[0] += bv[jt].w + mv[jt].x;
    c[1] += bv[jt].z + mv[jt].y;
    c[2] += bv[jt].y + mv[jt].z;
    c[3] += bv[jt].x + mv[jt].w;
    acc[jt] = c;
  }

  // Phase 2: in-register softmax
  float m = -1e30f;
#pragma unroll
  for (int jt = 0; jt < 9; ++jt)
    m = fmaxf(m, fmaxf(fmaxf(acc[jt][0], acc[jt][1]),
                       fmaxf(acc[jt][2], acc[jt][3])));
  m = fmaxf(m, __shfl_xor(m, 16));
  m = fmaxf(m, __shfl_xor(m, 32));
  float s = 0.f;
#pragma unroll
  for (int jt = 0; jt < 9; ++jt)
#pragma unroll
    for (int r = 0; r < 4; ++r) {
      acc[jt][r] = __expf(acc[jt][r] - m);
      s += acc[jt][r];
    }
  s += __shfl_xor(s, 16);
  s += __shfl_xor(s, 32);
  const float inv = 1.0f / s;

  uint wh_[10][2], wl_[10][2];
#pragma unroll
  for (int jt = 0; jt < 9; ++jt)
#pragma unroll
    for (int uu = 0; uu < 2; ++uu) {
      const float p0 = acc[jt][2 * uu] * inv, p1 = acc[jt][2 * uu + 1] * inv;
      const ushort h0 = bf16_rne(p0), h1 = bf16_rne(p1);
      const ushort l0 = bf16_rne(p0 - bf16_to_f(h0));
      const ushort l1 = bf16_rne(p1 - bf16_to_f(h1));
      wh_[jt][uu] = (uint)h0 | ((uint)h1 << 16);
      wl_[jt][uu] = (uint)l0 | ((uint)l1 << 16);
    }
  wh_[9][0] = 0; wh_[9][1] = 0; wl_[9][0] = 0; wl_[9][1] = 0;

  // Phase 3: PV via per-wave transpose scratch
  f32x4 oacc[2] = {(f32x4){0.f, 0.f, 0.f, 0.f}, (f32x4){0.f, 0.f, 0.f, 0.f}};
#pragma unroll
  for (int ks = 0; ks < 5; ++ks) {
    const int jtA = 2 * ks, jtB = 2 * ks + 1;
    *(uint2*)&scrw[rr * 20 + 2 * kg]           = make_uint2(wh_[jtA][0], wh_[jtA][1]);
    *(uint2*)&scrw[rr * 20 + 8 + 2 * kg]       = make_uint2(wh_[jtB][0], wh_[jtB][1]);
    *(uint2*)&scrw[320 + rr * 20 + 2 * kg]     = make_uint2(wl_[jtA][0], wl_[jtA][1]);
    *(uint2*)&scrw[320 + rr * 20 + 8 + 2 * kg] = make_uint2(wl_[jtB][0], wl_[jtB][1]);
    asm volatile("s_waitcnt lgkmcnt(0)" ::: "memory");
    const ushort* scr = (const ushort*)scrw;
    const short8 pfh = *(const short8*)&scr[rr * 40 + kg * 8];
    const short8 pfl = *(const short8*)&scr[640 + rr * 40 + kg * 8];
#pragma unroll
    for (int dt = 0; dt < 2; ++dt) {
      const short8 vfh = *(const short8*)&VtH[dt * 16 + rr][ks * 32 + kg * 8];
      const short8 vfl = *(const short8*)&VtL[dt * 16 + rr][ks * 32 + kg * 8];
      oacc[dt] = __builtin_amdgcn_mfma_f32_16x16x32_bf16(pfh, vfh, oacc[dt], 0, 0, 0);
      oacc[dt] = __builtin_amdgcn_mfma_f32_16x16x32_bf16(pfh, vfl, oacc[dt], 0, 0, 0);
      oacc[dt] = __builtin_amdgcn_mfma_f32_16x16x32_bf16(pfl, vfh, oacc[dt], 0, 0, 0);
    }
    asm volatile("s_waitcnt lgkmcnt(0)" ::: "memory");
  }

  // Fused proj partial: transpose O (i<->d across lanes) through the same
  // Scr ([16][40] hi + [16][40] lo), then A-frags feed 12 n-tiles of w2.
  {
    ushort* sh = (ushort*)scrw;
#pragma unroll
    for (int dt = 0; dt < 2; ++dt)
#pragma unroll
      for (int r = 0; r < 4; ++r) {
        const int il = kg * 4 + r;
        const int dl = dt * 16 + rr;
        const float v = oacc[dt][r];
        const ushort h = bf16_rne(v);
        sh[il * 40 + dl] = h;
        sh[640 + il * 40 + dl] = bf16_rne(v - bf16_to_f(h));
      }
    asm volatile("s_waitcnt lgkmcnt(0)" ::: "memory");
    const short8 pah = *(const short8*)&sh[rr * 40 + kg * 8];
    const short8 pal = *(const short8*)&sh[640 + rr * 40 + kg * 8];
#pragma unroll
    for (int nt = 0; nt < 12; ++nt) {
      const size_t gb = (size_t)(nt * 16 + rr) * 192 + u * 32 + kg * 8;
      const short8 wbh = *(const short8*)&w2h[gb];
      const short8 wbl = *(const short8*)&w2l[gb];
      pacc[nt] = __builtin_amdgcn_mfma_f32_16x16x32_bf16(pah, wbh, pacc[nt], 0, 0, 0);
      pacc[nt] = __builtin_amdgcn_mfma_f32_16x16x32_bf16(pah, wbl, pacc[nt], 0, 0, 0);
      pacc[nt] = __builtin_amdgcn_mfma_f32_16x16x32_bf16(pal, wbh, pacc[nt], 0, 0, 0);
    }
    asm volatile("s_waitcnt lgkmcnt(0)" ::: "memory");
  }
}

// K/V unpack-and-write helpers.
__device__ __forceinline__ void write_k(
    ushort (&KH)[144][40], ushort (&KL)[144][40], int l, int d, uint4 kv)
{
  ushort4 hk, lk;
  hk.x = (ushort)(kv.x >> 16); lk.x = (ushort)(kv.x & 0xffff);
  hk.y = (ushort)(kv.y >> 16); lk.y = (ushort)(kv.y & 0xffff);
  hk.z = (ushort)(kv.z >> 16); lk.z = (ushort)(kv.z & 0xffff);
  hk.w = (ushort)(kv.w >> 16); lk.w = (ushort)(kv.w & 0xffff);
  *(ushort4*)&KH[l][d] = hk;
  *(ushort4*)&KL[l][d] = lk;
}
__device__ __forceinline__ void write_vt(
    ushort (&VH)[32][168], ushort (&VL)[32][168], int l, int d, uint4 vv)
{
  VH[d + 0][l] = (ushort)(vv.x >> 16); VL[d + 0][l] = (ushort)(vv.x & 0xffff);
  VH[d + 1][l] = (ushort)(vv.y >> 16); VL[d + 1][l] = (ushort)(vv.y & 0xffff);
  VH[d + 2][l] = (ushort)(vv.z >> 16); VL[d + 2][l] = (ushort)(vv.z & 0xffff);
  VH[d + 3][l] = (ushort)(vv.w >> 16); VL[d + 3][l] = (ushort)(vv.w & 0xffff);
}

// ---------------------------------------------------------------------------
// attn+proj fused: 720 blocks x 576 thr. Block b -> window q=(b&7)*90+(b>>3);
// 6 heads sequential, ring of 2 K/V buffers; pacc accumulates proj across
// units; final epilogue adds b2 and writes fp32 out. LDS 112.1 KB.
// ---------------------------------------------------------------------------
__global__ __launch_bounds__(576) void attn_kernel(
    const uint* __restrict__ qp, const uint* __restrict__ kp,
    const uint* __restrict__ vp, const float* __restrict__ mask,
    const float* __restrict__ btT,
    const ushort* __restrict__ w2h, const ushort* __restrict__ w2l,
    const float* __restrict__ b2, float* __restrict__ out)
{
  __shared__ __align__(16) ushort Ks_[2][2][144][40];  // [buf][hi/lo]
  __shared__ __align__(16) ushort Vt[2][2][32][168];   // [buf][hi/lo][d][j]
  __shared__ __align__(16) uint Scr[9][640];           // per-wave scratch

  const int tid = threadIdx.x;
  const int wave = tid >> 6, lane = tid & 63;
  const int rr = lane & 15, kg = lane >> 4;

  const int b = blockIdx.x;
  const int w = (b & 7) * 90 + (b >> 3);   // bijective: 720 = 8*90
  const size_t base0 = (size_t)(w * 6) * 4608;
  const float* mrow = mask + (size_t)w * 20736;
  const float* brow0 = btT + (size_t)((w % 240) * 6) * 3312;
  float* out_b = out + (size_t)w * 144 * 192;

  const int l0 = tid >> 3, d0 = (tid & 7) * 4;
  const int f1 = tid + 576;
  const int l1 = f1 >> 3, d1 = (f1 & 7) * 4;

  // --- stage unit0 into buf0 ---
  {
    const uint4 kvA = *(const uint4*)&kp[base0 + l0 * 32 + d0];
    const uint4 vvA = *(const uint4*)&vp[base0 + l0 * 32 + d0];
    const uint4 kvB = *(const uint4*)&kp[base0 + l1 * 32 + d1];
    const uint4 vvB = *(const uint4*)&vp[base0 + l1 * 32 + d1];
    write_k(Ks_[0][0], Ks_[0][1], l0, d0, kvA);
    write_k(Ks_[0][0], Ks_[0][1], l1, d1, kvB);
    write_vt(Vt[0][0], Vt[0][1], l0, d0, vvA);
    write_vt(Vt[0][0], Vt[0][1], l1, d1, vvB);
  }
  // zero-pad j in [144,160) for both buffers & planes (2048 slots)
  for (int f = tid; f < 2048; f += 576) {
    const int bu = f >> 10, pl = (f >> 9) & 1, d = (f >> 4) & 31, j = 144 + (f & 15);
    Vt[bu][pl][d][j] = 0;
  }

  // proj accumulators (rows = this wave's i-strip, cols 0..191)
  f32x4 pacc[12];
#pragma unroll
  for (int nt = 0; nt < 12; ++nt) pacc[nt] = (f32x4){0.f, 0.f, 0.f, 0.f};

  // pending loads for unit1
  uint4 kA = *(const uint4*)&kp[base0 + 4608 + l0 * 32 + d0];
  uint4 vA = *(const uint4*)&vp[base0 + 4608 + l0 * 32 + d0];
  uint4 kB = *(const uint4*)&kp[base0 + 4608 + l1 * 32 + d1];
  uint4 vB = *(const uint4*)&vp[base0 + 4608 + l1 * 32 + d1];

  __syncthreads();  // buf0 ready

#pragma unroll
  for (int u = 0; u < 6; ++u) {
    attn_unit_fused(Ks_[u & 1][0], Ks_[u & 1][1], Vt[u & 1][0], Vt[u & 1][1],
                    Scr[wave], qp + base0 + (size_t)u * 4608, mrow,
                    brow0 + u * 3312, w2h, w2l, u, pacc, wave, rr, kg);
    if (u < 5) {
      // write pending regs into the ring buffer (freed by barrier below)
      write_k(Ks_[(u + 1) & 1][0], Ks_[(u + 1) & 1][1], l0, d0, kA);
      write_k(Ks_[(u + 1) & 1][0], Ks_[(u + 1) & 1][1], l1, d1, kB);
      write_vt(Vt[(u + 1) & 1][0], Vt[(u + 1) & 1][1], l0, d0, vA);
      write_vt(Vt[(u + 1) & 1][0], Vt[(u + 1) & 1][1], l1, d1, vB);
      if (u < 4) {
        kA = *(const uint4*)&kp[base0 + (size_t)(u + 2) * 4608 + l0 * 32 + d0];
        vA = *(const uint4*)&vp[base0 + (size_t)(u + 2) * 4608 + l0 * 32 + d0];
        kB = *(const uint4*)&kp[base0 + (size_t)(u + 2) * 4608 + l1 * 32 + d1];
        vB = *(const uint4*)&vp[base0 + (size_t)(u + 2) * 4608 + l1 * 32 + d1];
      }
      __syncthreads();  // next buffer ready
    }
  }

  // --- epilogue: out = pacc + b2 (fp32, coalesced 64B runs) ---
  const int i0 = wave * 16;
#pragma unroll
  for (int nt = 0; nt < 12; ++nt) {
    const int c = nt * 16 + rr;
    const float bcol = b2[c];
#pragma unroll
    for (int r = 0; r < 4; ++r)
      out_b[(size_t)(i0 + kg * 4 + r) * 192 + c] = pacc[nt][r] + bcol;
  }
}

// ---------------------------------------------------------------------------
extern "C" void kernel_launch(void* const* d_in, const int* in_sizes, int n_in,
                              void* d_out, int out_size, void* d_ws, size_t ws_size,
                              hipStream_t stream)
{
  const float* x    = (const float*)d_in[0];  // (720,144,192)
  const float* mask = (const float*)d_in[1];  // (720,144,144)
  const float* w1   = (const float*)d_in[2];  // (576,192)
  const float* b1   = (const float*)d_in[3];  // (576,)
  const float* w2   = (const float*)d_in[4];  // (192,192)
  const float* b2   = (const float*)d_in[5];  // (192,)
  const float* bt   = (const float*)d_in[6];  // (3312,240,6)
  float* out = (float*)d_out;

  // ws layout: qp/kp/vp packed-uint (3 x 79.6 MB); 4th region (ex-aop) hosts:
  //   w1 planes at offset 0 (read by qkv, then dead),
  //   btT at float-offset 1,000,000 (19.1 MB, read by attn),
  //   w2 planes at float-offset 6,000,000 (147 KB, read by attn).
  uint* qp  = (uint*)d_ws;
  uint* kp  = qp + kQKVElems;
  uint* vp  = kp + kQKVElems;
  uint* scratch = vp + kQKVElems;  // 19,906,560 uints
  ushort* w1h = (ushort*)scratch;
  ushort* w1l = w1h + 110592;
  float* btT = (float*)scratch + 1000000;       // 1e6+4,769,280 < 6e6
  ushort* w2h = (ushort*)((float*)scratch + 6000000);
  ushort* w2l = w2h + 36864;

  btT_kernel<<<69 * 30, 256, 0, stream>>>(bt, btT);
  prep_kernel<<<432, 256, 0, stream>>>(w1, w1h, w1l, 110592);
  prep_kernel<<<144, 256, 0, stream>>>(w2, w2h, w2l, 36864);
  qkv_gemm_kernel<<<810 * 3, 512, 0, stream>>>(x, w1h, w1l, b1, qp, kp, vp);
  attn_kernel<<<720, 576, 0, stream>>>(qp, kp, vp, mask, btT, w2h, w2l, b2, out);
}